// Round 4
// baseline (104.785 us; speedup 1.0000x reference)
//
#include <hip/hip_runtime.h>

// MaxSel: max over 4 directional 3x3 Laplacians, zero-padded, 48x 512x512 fp32 images.
// Memory-bound stencil (~101 MB HBM traffic, 16 us floor at 6.3 TB/s).
// Each thread computes a 4-row x 8-col output patch using a 3-row register window
// over 6 input rows (2x float4 + 2 scalar halo loads per row = 0.75 loads/output).
// Plain (non-NT) stores: A/B vs round 3 showed NT stores were ~3us slower.

#define HH 512
#define WW 512
#define IMG (HH * WW)

typedef float v4f __attribute__((ext_vector_type(4)));

struct Row {
    float c[8];  // two aligned quads
    float l, r;  // halo: w-1 and w+8
};

__device__ __forceinline__ float getv(const Row& rw, int j) {
    // j in [-1, 8]; resolved at compile time under full unroll
    if (j < 0) return rw.l;
    if (j > 7) return rw.r;
    return rw.c[j];
}

__global__ __launch_bounds__(256) void lapmax_kernel(const float* __restrict__ x,
                                                     float* __restrict__ out) {
    const int tid = blockIdx.x * 256 + threadIdx.x;
    const int wq  = tid & 63;           // 64 groups of 8 columns
    const int rg  = (tid >> 6) & 127;   // 128 row-groups of 4 rows
    const int img = tid >> 13;          // 48 images

    const int w  = wq << 3;
    const int h0 = rg << 2;

    const float* base  = x   + (size_t)img * IMG;
    float*       obase = out + (size_t)img * IMG;

    Row rows[3];

#pragma unroll
    for (int k = 0; k < 6; ++k) {
        const int r = h0 - 1 + k;
        Row& rw = rows[k % 3];
        if (r >= 0 && r < HH) {
            const float* p = base + r * WW + w;
            const v4f v0 = *reinterpret_cast<const v4f*>(p);
            const v4f v1 = *reinterpret_cast<const v4f*>(p + 4);
            rw.c[0] = v0.x; rw.c[1] = v0.y; rw.c[2] = v0.z; rw.c[3] = v0.w;
            rw.c[4] = v1.x; rw.c[5] = v1.y; rw.c[6] = v1.z; rw.c[7] = v1.w;
            rw.l = (w > 0)       ? p[-1] : 0.0f;
            rw.r = (w < WW - 8)  ? p[8]  : 0.0f;
        } else {
#pragma unroll
            for (int j = 0; j < 8; ++j) rw.c[j] = 0.0f;
            rw.l = 0.0f; rw.r = 0.0f;
        }

        if (k >= 2) {
            const Row& up  = rows[(k - 2) % 3];
            const Row& mid = rows[(k - 1) % 3];
            const Row& dn  = rows[k % 3];
            float o[8];
#pragma unroll
            for (int j = 0; j < 8; ++j) {
                const float sh  = getv(mid, j - 1) + getv(mid, j + 1); // horizontal
                const float sv  = getv(up,  j)     + getv(dn,  j);     // vertical
                const float sd1 = getv(up,  j + 1) + getv(dn,  j - 1); // anti-diag
                const float sd2 = getv(up,  j - 1) + getv(dn,  j + 1); // main diag
                const float m = fmaxf(fmaxf(sh, sv), fmaxf(sd1, sd2));
                o[j] = fmaf(-2.0f, mid.c[j], m);
            }
            const int orow = h0 + k - 2;
            float* po = obase + (size_t)orow * WW + w;
            const v4f a = {o[0], o[1], o[2], o[3]};
            const v4f b = {o[4], o[5], o[6], o[7]};
            *reinterpret_cast<v4f*>(po)     = a;
            *reinterpret_cast<v4f*>(po + 4) = b;
        }
    }
}

extern "C" void kernel_launch(void* const* d_in, const int* in_sizes, int n_in,
                              void* d_out, int out_size, void* d_ws, size_t ws_size,
                              hipStream_t stream) {
    const float* x = (const float*)d_in[0];
    float* out = (float*)d_out;

    // total elements = nimg * 512 * 512; each thread covers 32 outputs (4x8 patch)
    const int total    = in_sizes[0];
    const int nthreads = total / 32;
    const int blocks   = (nthreads + 255) / 256;

    lapmax_kernel<<<blocks, 256, 0, stream>>>(x, out);
}

// Round 5
// 101.284 us; speedup vs baseline: 1.0346x; 1.0346x over previous
//
#include <hip/hip_runtime.h>

// MaxSel: max over 4 directional 3x3 Laplacians, zero-padded, 48x 512x512 fp32 images.
// Memory-bound stencil (~101 MB HBM traffic, ~16 us floor at 6.3 TB/s).
// Each thread computes a 4-row x 4-col output patch using a 3-row register window
// over 6 input rows (1 float4 + 2 scalar halo loads per row).
// A/B history: 4x4 patch = 100.5us total; 4x8 patch = 104.2/104.8us (wave's load
// span 2KiB vs dense 1KiB, half the waves) -> keep 4x4. NT stores: neutral.

#define HH 512
#define WW 512
#define IMG (HH * WW)

struct Row {
    float c[4];  // aligned quad
    float l, r;  // halo: w-1 and w+4
};

__device__ __forceinline__ float getv(const Row& rw, int j) {
    // j in [-1, 4]; resolved at compile time under full unroll
    if (j < 0) return rw.l;
    if (j > 3) return rw.r;
    return rw.c[j];
}

__global__ __launch_bounds__(256) void lapmax_kernel(const float* __restrict__ x,
                                                     float* __restrict__ out) {
    const int tid = blockIdx.x * 256 + threadIdx.x;
    const int wq  = tid & 127;          // 128 quads of 4 columns
    const int rg  = (tid >> 7) & 127;   // 128 row-groups of 4 rows
    const int img = tid >> 14;          // 48 images

    const int w  = wq << 2;
    const int h0 = rg << 2;

    const float* base  = x   + (size_t)img * IMG;
    float*       obase = out + (size_t)img * IMG;

    Row rows[3];

#pragma unroll
    for (int k = 0; k < 6; ++k) {
        const int r = h0 - 1 + k;
        Row& rw = rows[k % 3];
        if (r >= 0 && r < HH) {
            const float* p = base + r * WW + w;
            const float4 v = *reinterpret_cast<const float4*>(p);
            rw.c[0] = v.x; rw.c[1] = v.y; rw.c[2] = v.z; rw.c[3] = v.w;
            rw.l = (w > 0)       ? p[-1] : 0.0f;
            rw.r = (w < WW - 4)  ? p[4]  : 0.0f;
        } else {
            rw.c[0] = rw.c[1] = rw.c[2] = rw.c[3] = 0.0f;
            rw.l = 0.0f; rw.r = 0.0f;
        }

        if (k >= 2) {
            const Row& up  = rows[(k - 2) % 3];
            const Row& mid = rows[(k - 1) % 3];
            const Row& dn  = rows[k % 3];
            float o[4];
#pragma unroll
            for (int j = 0; j < 4; ++j) {
                const float sh  = getv(mid, j - 1) + getv(mid, j + 1); // horizontal
                const float sv  = getv(up,  j)     + getv(dn,  j);     // vertical
                const float sd1 = getv(up,  j + 1) + getv(dn,  j - 1); // anti-diag
                const float sd2 = getv(up,  j - 1) + getv(dn,  j + 1); // main diag
                const float m = fmaxf(fmaxf(sh, sv), fmaxf(sd1, sd2));
                o[j] = fmaf(-2.0f, mid.c[j], m);
            }
            const int orow = h0 + k - 2;
            *reinterpret_cast<float4*>(obase + (size_t)orow * WW + w) =
                make_float4(o[0], o[1], o[2], o[3]);
        }
    }
}

extern "C" void kernel_launch(void* const* d_in, const int* in_sizes, int n_in,
                              void* d_out, int out_size, void* d_ws, size_t ws_size,
                              hipStream_t stream) {
    const float* x = (const float*)d_in[0];
    float* out = (float*)d_out;

    // total elements = nimg * 512 * 512; each thread covers 16 outputs (4x4 patch)
    const int total    = in_sizes[0];
    const int nthreads = total / 16;
    const int blocks   = (nthreads + 255) / 256;

    lapmax_kernel<<<blocks, 256, 0, stream>>>(x, out);
}